// Round 1
// baseline (7210.771 us; speedup 1.0000x reference)
//
#include <hip/hip_runtime.h>
#include <hip/hip_bf16.h>
#include <math.h>

#define NT 64  // nodes per block tile

// ---------------- embedding: x0 = concat(emb_deg[deg], emb_lab[lab]) ----------------
__global__ __launch_bounds__(256) void embed_kernel(
    const int* __restrict__ deg, const int* __restrict__ lab,
    const float* __restrict__ ed, const float* __restrict__ el,
    float* __restrict__ x0, int n) {
  int idx = blockIdx.x * 256 + threadIdx.x;
  if (idx >= n * 128) return;
  int node = idx >> 7, d = idx & 127;
  float v = (d < 64) ? ed[deg[node] * 64 + d] : el[lab[node] * 64 + (d - 64)];
  x0[idx] = v;
}

// ---------------- CSR build ----------------
__global__ __launch_bounds__(256) void hist_kernel(const int* __restrict__ dst,
                                                   int* __restrict__ counts, int E) {
  int e = blockIdx.x * 256 + threadIdx.x;
  if (e < E) atomicAdd(&counts[dst[e]], 1);
}

// per-block inclusive scan of 2048 elements (256 threads x 8)
__global__ __launch_bounds__(256) void scan1_kernel(const int* __restrict__ counts,
                                                    int* __restrict__ rowptr,
                                                    int* __restrict__ bsums, int n) {
  __shared__ int lds[256];
  int tid = threadIdx.x;
  int base = blockIdx.x * 2048;
  int vals[8];
  int s = 0;
#pragma unroll
  for (int k = 0; k < 8; ++k) {
    int idx = base + tid * 8 + k;
    vals[k] = (idx < n) ? counts[idx] : 0;
    s += vals[k];
  }
  lds[tid] = s;
  __syncthreads();
  for (int off = 1; off < 256; off <<= 1) {
    int v = (tid >= off) ? lds[tid - off] : 0;
    __syncthreads();
    lds[tid] += v;
    __syncthreads();
  }
  int run = lds[tid] - s;  // exclusive prefix of this thread's chunk
#pragma unroll
  for (int k = 0; k < 8; ++k) {
    int idx = base + tid * 8 + k;
    run += vals[k];
    if (idx < n) rowptr[idx + 1] = run;  // per-block inclusive
  }
  if (tid == 255) bsums[blockIdx.x] = lds[255];
}

__global__ void scan2_kernel(const int* __restrict__ bsums, int* __restrict__ boffs, int nb) {
  if (threadIdx.x == 0) {
    int run = 0;
    for (int i = 0; i < nb; ++i) { boffs[i] = run; run += bsums[i]; }
  }
}

__global__ __launch_bounds__(256) void scan3_kernel(int* __restrict__ rowptr,
                                                    const int* __restrict__ boffs, int n) {
  int idx = blockIdx.x * 256 + threadIdx.x;
  if (idx == 0) rowptr[0] = 0;
  if (idx < n) rowptr[idx + 1] += boffs[idx >> 11];
}

__global__ __launch_bounds__(256) void cursor_kernel(int* __restrict__ cursor,
                                                     const int* __restrict__ rowptr, int n) {
  int idx = blockIdx.x * 256 + threadIdx.x;
  if (idx < n) cursor[idx] = rowptr[idx];
}

__global__ __launch_bounds__(256) void scatter_kernel(const int* __restrict__ src,
                                                      const int* __restrict__ dst,
                                                      int* __restrict__ cursor,
                                                      int* __restrict__ colidx, int E) {
  int e = blockIdx.x * 256 + threadIdx.x;
  if (e < E) {
    int d = dst[e];
    int pos = atomicAdd(&cursor[d], 1);
    colidx[pos] = src[e];
  }
}

// ---------------- fused GIN layer: h = (x + agg) @ W^T + b, plus BN partial stats ------
// stats layout per layer: [sum 64][sumsq 64][scale 64][shift 64]
template <int DIN>
__global__ __launch_bounds__(256) void gin_layer_kernel(
    const float* __restrict__ x, const int* __restrict__ rowptr,
    const int* __restrict__ colidx, const float* __restrict__ W,
    const float* __restrict__ bias, float* __restrict__ h,
    float* __restrict__ stats, int n) {
  __shared__ float tileT[DIN][NT + 4];  // [d][r]
  __shared__ float WT[DIN][NT + 4];     // [d][o]
  __shared__ float s_sum[64], s_sq[64];

  int tid = threadIdx.x;
  // load W transposed (W is [64][DIN] row-major)
  constexpr int SH = (DIN == 128) ? 7 : 6;
  for (int t = tid; t < 64 * DIN; t += 256) {
    int o = t >> SH, d = t & (DIN - 1);
    WT[d][o] = W[t];
  }
  if (tid < 64) { s_sum[tid] = 0.f; s_sq[tid] = 0.f; }

  int nbase = blockIdx.x * NT;
  int lane = tid & 63, wave = tid >> 6;
  for (int k = wave; k < NT; k += 4) {
    int node = nbase + k;
    float a0 = 0.f, a1 = 0.f;
    if (node < n) {
      a0 = x[(size_t)node * DIN + lane];
      if (DIN == 128) a1 = x[(size_t)node * DIN + 64 + lane];
      int beg = rowptr[node], end = rowptr[node + 1];
      for (int e = beg; e < end; ++e) {
        int j = colidx[e];
        a0 += x[(size_t)j * DIN + lane];
        if (DIN == 128) a1 += x[(size_t)j * DIN + 64 + lane];
      }
    }
    tileT[lane][k] = a0;
    if (DIN == 128) tileT[64 + lane][k] = a1;
  }
  __syncthreads();

  int o0 = (tid & 15) * 4, r0 = (tid >> 4) * 4;
  float acc[4][4] = {};
#pragma unroll
  for (int d = 0; d < DIN; ++d) {
    const float4 wv = *(const float4*)(&WT[d][o0]);
    const float4 tv = *(const float4*)(&tileT[d][r0]);
    acc[0][0] += wv.x * tv.x; acc[0][1] += wv.x * tv.y; acc[0][2] += wv.x * tv.z; acc[0][3] += wv.x * tv.w;
    acc[1][0] += wv.y * tv.x; acc[1][1] += wv.y * tv.y; acc[1][2] += wv.y * tv.z; acc[1][3] += wv.y * tv.w;
    acc[2][0] += wv.z * tv.x; acc[2][1] += wv.z * tv.y; acc[2][2] += wv.z * tv.z; acc[2][3] += wv.z * tv.w;
    acc[3][0] += wv.w * tv.x; acc[3][1] += wv.w * tv.y; acc[3][2] += wv.w * tv.z; acc[3][3] += wv.w * tv.w;
  }

  // epilogue: bias, write h, partial BN stats
#pragma unroll
  for (int i = 0; i < 4; ++i) {
    float bv = bias[o0 + i];
    float s = 0.f, q = 0.f;
#pragma unroll
    for (int j = 0; j < 4; ++j) {
      int node = nbase + r0 + j;
      if (node < n) {
        float v = acc[i][j] + bv;
        h[(size_t)node * 64 + o0 + i] = v;
        s += v;
        q += v * v;
      }
    }
    atomicAdd(&s_sum[o0 + i], s);
    atomicAdd(&s_sq[o0 + i], q);
  }
  __syncthreads();
  if (tid < 64) {
    atomicAdd(&stats[tid], s_sum[tid]);
    atomicAdd(&stats[64 + tid], s_sq[tid]);
  }
}

// ---------------- final MLP over concat [x0|z1|z2|z3] (320 -> 64) ----------------
__global__ __launch_bounds__(256) void final_mlp_kernel(
    const float* __restrict__ x0, const float* __restrict__ z1,
    const float* __restrict__ z2, const float* __restrict__ z3,
    const float* __restrict__ fw1, const float* __restrict__ fb1,
    float* __restrict__ h, float* __restrict__ stats, int n) {
  __shared__ float tileT[128][NT + 4];
  __shared__ float WT[128][NT + 4];
  __shared__ float s_sum[64], s_sq[64];

  int tid = threadIdx.x;
  if (tid < 64) { s_sum[tid] = 0.f; s_sq[tid] = 0.f; }
  int nbase = blockIdx.x * NT;
  int lane = tid & 63, wave = tid >> 6;
  int o0 = (tid & 15) * 4, r0 = (tid >> 4) * 4;
  float acc[4][4] = {};

  const float* srcs[4] = {x0, z1, z2, z3};
  const int dins[4] = {128, 64, 64, 64};
  int woff = 0;
  for (int seg = 0; seg < 4; ++seg) {
    const float* src = srcs[seg];
    int DIN = dins[seg];
    int sh = (DIN == 128) ? 7 : 6;
    __syncthreads();
    for (int t = tid; t < 64 * DIN; t += 256) {
      int o = t >> sh, d = t & (DIN - 1);
      WT[d][o] = fw1[o * 320 + woff + d];
    }
    for (int k = wave; k < NT; k += 4) {
      int node = nbase + k;
      float a0 = 0.f, a1 = 0.f;
      if (node < n) {
        a0 = src[(size_t)node * DIN + lane];
        if (DIN == 128) a1 = src[(size_t)node * DIN + 64 + lane];
      }
      tileT[lane][k] = a0;
      if (DIN == 128) tileT[64 + lane][k] = a1;
    }
    __syncthreads();
    for (int d = 0; d < DIN; ++d) {
      const float4 wv = *(const float4*)(&WT[d][o0]);
      const float4 tv = *(const float4*)(&tileT[d][r0]);
      acc[0][0] += wv.x * tv.x; acc[0][1] += wv.x * tv.y; acc[0][2] += wv.x * tv.z; acc[0][3] += wv.x * tv.w;
      acc[1][0] += wv.y * tv.x; acc[1][1] += wv.y * tv.y; acc[1][2] += wv.y * tv.z; acc[1][3] += wv.y * tv.w;
      acc[2][0] += wv.z * tv.x; acc[2][1] += wv.z * tv.y; acc[2][2] += wv.z * tv.z; acc[2][3] += wv.z * tv.w;
      acc[3][0] += wv.w * tv.x; acc[3][1] += wv.w * tv.y; acc[3][2] += wv.w * tv.z; acc[3][3] += wv.w * tv.w;
    }
    woff += DIN;
  }

#pragma unroll
  for (int i = 0; i < 4; ++i) {
    float bv = fb1[o0 + i];
    float s = 0.f, q = 0.f;
#pragma unroll
    for (int j = 0; j < 4; ++j) {
      int node = nbase + r0 + j;
      if (node < n) {
        float v = acc[i][j] + bv;
        h[(size_t)node * 64 + o0 + i] = v;
        s += v;
        q += v * v;
      }
    }
    atomicAdd(&s_sum[o0 + i], s);
    atomicAdd(&s_sq[o0 + i], q);
  }
  __syncthreads();
  if (tid < 64) {
    atomicAdd(&stats[tid], s_sum[tid]);
    atomicAdd(&stats[64 + tid], s_sq[tid]);
  }
}

// ---------------- BN finalize: scale/shift ----------------
__global__ void bn_finalize_kernel(float* __restrict__ st, const float* __restrict__ g,
                                   const float* __restrict__ be, float inv_n) {
  int o = threadIdx.x;
  if (o < 64) {
    float mean = st[o] * inv_n;
    float var = st[64 + o] * inv_n - mean * mean;
    float sc = g[o] * rsqrtf(var + 1e-5f);
    st[128 + o] = sc;
    st[192 + o] = be[o] - mean * sc;
  }
}

// ---------------- BN apply + leaky ----------------
__global__ __launch_bounds__(256) void bn_apply_kernel(const float* __restrict__ h,
                                                       const float* __restrict__ st,
                                                       float* __restrict__ z, int total) {
  int idx = blockIdx.x * 256 + threadIdx.x;
  if (idx < total) {
    int o = idx & 63;
    float v = h[idx] * st[128 + o] + st[192 + o];
    z[idx] = (v >= 0.f) ? v : 0.01f * v;
  }
}

// ---------------- final head: sigmoid(leaky(bn(h)) @ fw2^T + fb2) ----------------
__global__ __launch_bounds__(256) void final_out_kernel(const float* __restrict__ h,
                                                        const float* __restrict__ st,
                                                        const float* __restrict__ fw2,
                                                        const float* __restrict__ fb2,
                                                        float* __restrict__ out, int n) {
  int lane = threadIdx.x & 63;
  int node = blockIdx.x * 4 + (threadIdx.x >> 6);
  if (node >= n) return;
  float v = h[(size_t)node * 64 + lane] * st[128 + lane] + st[192 + lane];
  v = (v >= 0.f) ? v : 0.01f * v;
  v *= fw2[lane];
#pragma unroll
  for (int off = 32; off > 0; off >>= 1) v += __shfl_xor(v, off);
  if (lane == 0) out[node] = 1.f / (1.f + expf(-(v + fb2[0])));
}

extern "C" void kernel_launch(void* const* d_in, const int* in_sizes, int n_in,
                              void* d_out, int out_size, void* d_ws, size_t ws_size,
                              hipStream_t stream) {
  const int* node_deg = (const int*)d_in[0];
  const int* node_lab = (const int*)d_in[1];
  const int* ei = (const int*)d_in[2];
  const float* emb_deg = (const float*)d_in[3];
  const float* emb_lab = (const float*)d_in[4];
  const float* w0 = (const float*)d_in[5];
  const float* b0 = (const float*)d_in[6];
  const float* g0 = (const float*)d_in[7];
  const float* be0 = (const float*)d_in[8];
  const float* w1 = (const float*)d_in[9];
  const float* b1 = (const float*)d_in[10];
  const float* g1 = (const float*)d_in[11];
  const float* be1 = (const float*)d_in[12];
  const float* w2 = (const float*)d_in[13];
  const float* b2 = (const float*)d_in[14];
  const float* g2 = (const float*)d_in[15];
  const float* be2 = (const float*)d_in[16];
  const float* fw1 = (const float*)d_in[17];
  const float* fb1 = (const float*)d_in[18];
  const float* fg = (const float*)d_in[19];
  const float* fbe = (const float*)d_in[20];
  const float* fw2 = (const float*)d_in[21];
  const float* fb2 = (const float*)d_in[22];

  const int N = in_sizes[0];
  const int E = in_sizes[2] / 2;
  const int* src = ei;
  const int* dst = ei + E;

  // workspace layout
  char* ws = (char*)d_ws;
  size_t off = 0;
  auto alloc = [&](size_t bytes) {
    void* p = ws + off;
    off += (bytes + 255) & ~(size_t)255;
    return p;
  };
  float* x0 = (float*)alloc((size_t)N * 128 * 4);
  float* z1 = (float*)alloc((size_t)N * 64 * 4);
  float* z2 = (float*)alloc((size_t)N * 64 * 4);
  float* z3 = (float*)alloc((size_t)N * 64 * 4);
  float* h = (float*)alloc((size_t)N * 64 * 4);
  int* rowptr = (int*)alloc((size_t)(N + 1) * 4);
  int* cursor = (int*)alloc((size_t)N * 4);
  int* counts = (int*)alloc((size_t)N * 4);
  int* colidx = (int*)alloc((size_t)E * 4);
  int* bsums = (int*)alloc(64 * 4);
  int* boffs = (int*)alloc(64 * 4);
  float* stats = (float*)alloc(4 * 256 * 4);  // 4 layers x [sum|sumsq|scale|shift]

  hipMemsetAsync(counts, 0, (size_t)N * 4, stream);
  hipMemsetAsync(stats, 0, 4 * 256 * 4, stream);

  embed_kernel<<<(N * 128 + 255) / 256, 256, 0, stream>>>(node_deg, node_lab, emb_deg,
                                                          emb_lab, x0, N);
  hist_kernel<<<(E + 255) / 256, 256, 0, stream>>>(dst, counts, E);
  int nb = (N + 2047) / 2048;
  scan1_kernel<<<nb, 256, 0, stream>>>(counts, rowptr, bsums, N);
  scan2_kernel<<<1, 64, 0, stream>>>(bsums, boffs, nb);
  scan3_kernel<<<(N + 255) / 256, 256, 0, stream>>>(rowptr, boffs, N);
  cursor_kernel<<<(N + 255) / 256, 256, 0, stream>>>(cursor, rowptr, N);
  scatter_kernel<<<(E + 255) / 256, 256, 0, stream>>>(src, dst, cursor, colidx, E);

  int ngrid = (N + NT - 1) / NT;
  // layer 0: 128 -> 64
  gin_layer_kernel<128><<<ngrid, 256, 0, stream>>>(x0, rowptr, colidx, w0, b0, h, stats, N);
  bn_finalize_kernel<<<1, 64, 0, stream>>>(stats, g0, be0, 1.0f / N);
  bn_apply_kernel<<<(N * 64 + 255) / 256, 256, 0, stream>>>(h, stats, z1, N * 64);
  // layer 1: 64 -> 64
  gin_layer_kernel<64><<<ngrid, 256, 0, stream>>>(z1, rowptr, colidx, w1, b1, h, stats + 256, N);
  bn_finalize_kernel<<<1, 64, 0, stream>>>(stats + 256, g1, be1, 1.0f / N);
  bn_apply_kernel<<<(N * 64 + 255) / 256, 256, 0, stream>>>(h, stats + 256, z2, N * 64);
  // layer 2: 64 -> 64
  gin_layer_kernel<64><<<ngrid, 256, 0, stream>>>(z2, rowptr, colidx, w2, b2, h, stats + 512, N);
  bn_finalize_kernel<<<1, 64, 0, stream>>>(stats + 512, g2, be2, 1.0f / N);
  bn_apply_kernel<<<(N * 64 + 255) / 256, 256, 0, stream>>>(h, stats + 512, z3, N * 64);
  // final MLP 320 -> 64
  final_mlp_kernel<<<ngrid, 256, 0, stream>>>(x0, z1, z2, z3, fw1, fb1, h, stats + 768, N);
  bn_finalize_kernel<<<1, 64, 0, stream>>>(stats + 768, fg, fbe, 1.0f / N);
  final_out_kernel<<<(N + 3) / 4, 256, 0, stream>>>(h, stats + 768, fw2, fb2, (float*)d_out, N);
}

// Round 2
// 942.875 us; speedup vs baseline: 7.6476x; 7.6476x over previous
//
#include <hip/hip_runtime.h>
#include <math.h>

#define NT 64  // nodes per GEMM block tile

// ---------------- embedding: x0 = concat(emb_deg[deg], emb_lab[lab]) ----------------
__global__ __launch_bounds__(256) void embed_kernel(
    const int* __restrict__ deg, const int* __restrict__ lab,
    const float* __restrict__ ed, const float* __restrict__ el,
    float4* __restrict__ x0, int n) {
  int idx4 = blockIdx.x * 256 + threadIdx.x;  // one float4 per thread
  if (idx4 >= n * 32) return;                 // 128 floats = 32 float4 per node
  int node = idx4 >> 5, q = idx4 & 31;
  const float* srcp = (q < 16) ? (ed + (size_t)deg[node] * 64 + q * 4)
                               : (el + (size_t)lab[node] * 64 + (q - 16) * 4);
  x0[idx4] = *(const float4*)srcp;
}

// ---------------- CSR build ----------------
__global__ __launch_bounds__(256) void hist_kernel(const int* __restrict__ dst,
                                                   int* __restrict__ counts, int E) {
  int e = blockIdx.x * 256 + threadIdx.x;
  if (e < E) atomicAdd(&counts[dst[e]], 1);
}

__global__ __launch_bounds__(256) void scan1_kernel(const int* __restrict__ counts,
                                                    int* __restrict__ rowptr,
                                                    int* __restrict__ bsums, int n) {
  __shared__ int lds[256];
  int tid = threadIdx.x;
  int base = blockIdx.x * 2048;
  int vals[8];
  int s = 0;
#pragma unroll
  for (int k = 0; k < 8; ++k) {
    int idx = base + tid * 8 + k;
    vals[k] = (idx < n) ? counts[idx] : 0;
    s += vals[k];
  }
  lds[tid] = s;
  __syncthreads();
  for (int off = 1; off < 256; off <<= 1) {
    int v = (tid >= off) ? lds[tid - off] : 0;
    __syncthreads();
    lds[tid] += v;
    __syncthreads();
  }
  int run = lds[tid] - s;
#pragma unroll
  for (int k = 0; k < 8; ++k) {
    int idx = base + tid * 8 + k;
    run += vals[k];
    if (idx < n) rowptr[idx + 1] = run;
  }
  if (tid == 255) bsums[blockIdx.x] = lds[255];
}

__global__ void scan2_kernel(const int* __restrict__ bsums, int* __restrict__ boffs, int nb) {
  if (threadIdx.x == 0) {
    int run = 0;
    for (int i = 0; i < nb; ++i) { boffs[i] = run; run += bsums[i]; }
  }
}

__global__ __launch_bounds__(256) void scan3_kernel(int* __restrict__ rowptr,
                                                    const int* __restrict__ boffs, int n) {
  int idx = blockIdx.x * 256 + threadIdx.x;
  if (idx == 0) rowptr[0] = 0;
  if (idx < n) rowptr[idx + 1] += boffs[idx >> 11];
}

__global__ __launch_bounds__(256) void cursor_kernel(int* __restrict__ cursor,
                                                     const int* __restrict__ rowptr, int n) {
  int idx = blockIdx.x * 256 + threadIdx.x;
  if (idx < n) cursor[idx] = rowptr[idx];
}

__global__ __launch_bounds__(256) void scatter_kernel(const int* __restrict__ src,
                                                      const int* __restrict__ dst,
                                                      int* __restrict__ cursor,
                                                      int* __restrict__ colidx, int E) {
  int e = blockIdx.x * 256 + threadIdx.x;
  if (e < E) {
    int d = dst[e];
    int pos = atomicAdd(&cursor[d], 1);
    colidx[pos] = src[e];
  }
}

// ---------------- GEMM 0: y = x0 @ W^T   (DIN=128, no input transform) ----------------
__global__ __launch_bounds__(256) void gemm0_kernel(
    const float* __restrict__ x, const float* __restrict__ W,
    float* __restrict__ y, int n) {
  __shared__ float tileT[128][NT + 4];
  __shared__ float WT[128][NT + 4];
  int tid = threadIdx.x;
  for (int t = tid; t < 64 * 128; t += 256) {
    int o = t >> 7, d = t & 127;
    WT[d][o] = W[t];
  }
  int nbase = blockIdx.x * NT;
  int lane = tid & 63, wave = tid >> 6;
  for (int k = wave; k < NT; k += 4) {
    int node = nbase + k;
    float a0 = 0.f, a1 = 0.f;
    if (node < n) {
      a0 = x[(size_t)node * 128 + lane];
      a1 = x[(size_t)node * 128 + 64 + lane];
    }
    tileT[lane][k] = a0;
    tileT[64 + lane][k] = a1;
  }
  __syncthreads();
  int o0 = (tid & 15) * 4, r0 = (tid >> 4) * 4;
  float acc[4][4] = {};
#pragma unroll 8
  for (int d = 0; d < 128; ++d) {
    const float4 wv = *(const float4*)(&WT[d][o0]);
    const float4 tv = *(const float4*)(&tileT[d][r0]);
    acc[0][0] += wv.x * tv.x; acc[0][1] += wv.x * tv.y; acc[0][2] += wv.x * tv.z; acc[0][3] += wv.x * tv.w;
    acc[1][0] += wv.y * tv.x; acc[1][1] += wv.y * tv.y; acc[1][2] += wv.y * tv.z; acc[1][3] += wv.y * tv.w;
    acc[2][0] += wv.z * tv.x; acc[2][1] += wv.z * tv.y; acc[2][2] += wv.z * tv.z; acc[2][3] += wv.z * tv.w;
    acc[3][0] += wv.w * tv.x; acc[3][1] += wv.w * tv.y; acc[3][2] += wv.w * tv.z; acc[3][3] += wv.w * tv.w;
  }
#pragma unroll
  for (int i = 0; i < 4; ++i)
#pragma unroll
    for (int j = 0; j < 4; ++j) {
      int node = nbase + r0 + j;
      if (node < n) y[(size_t)node * 64 + o0 + i] = acc[i][j];
    }
}

// ------- GEMM (layers 1,2): z = leaky(bn(hin)); y = z @ W^T; also write z -------
__global__ __launch_bounds__(256) void gemm_bn_kernel(
    const float* __restrict__ hin, const float* __restrict__ st,
    const float* __restrict__ W, float* __restrict__ z,
    float* __restrict__ y, int n) {
  __shared__ float tileT[64][NT + 4];
  __shared__ float WT[64][NT + 4];
  int tid = threadIdx.x;
  for (int t = tid; t < 64 * 64; t += 256) {
    int o = t >> 6, d = t & 63;
    WT[d][o] = W[t];
  }
  int nbase = blockIdx.x * NT;
  int lane = tid & 63, wave = tid >> 6;
  float sc = st[128 + lane], sh = st[192 + lane];
  for (int k = wave; k < NT; k += 4) {
    int node = nbase + k;
    float v = 0.f;
    if (node < n) {
      v = hin[(size_t)node * 64 + lane] * sc + sh;
      v = (v >= 0.f) ? v : 0.01f * v;
      z[(size_t)node * 64 + lane] = v;
    }
    tileT[lane][k] = v;
  }
  __syncthreads();
  int o0 = (tid & 15) * 4, r0 = (tid >> 4) * 4;
  float acc[4][4] = {};
#pragma unroll 8
  for (int d = 0; d < 64; ++d) {
    const float4 wv = *(const float4*)(&WT[d][o0]);
    const float4 tv = *(const float4*)(&tileT[d][r0]);
    acc[0][0] += wv.x * tv.x; acc[0][1] += wv.x * tv.y; acc[0][2] += wv.x * tv.z; acc[0][3] += wv.x * tv.w;
    acc[1][0] += wv.y * tv.x; acc[1][1] += wv.y * tv.y; acc[1][2] += wv.y * tv.z; acc[1][3] += wv.y * tv.w;
    acc[2][0] += wv.z * tv.x; acc[2][1] += wv.z * tv.y; acc[2][2] += wv.z * tv.z; acc[2][3] += wv.z * tv.w;
    acc[3][0] += wv.w * tv.x; acc[3][1] += wv.w * tv.y; acc[3][2] += wv.w * tv.z; acc[3][3] += wv.w * tv.w;
  }
#pragma unroll
  for (int i = 0; i < 4; ++i)
#pragma unroll
    for (int j = 0; j < 4; ++j) {
      int node = nbase + r0 + j;
      if (node < n) y[(size_t)node * 64 + o0 + i] = acc[i][j];
    }
}

// ---------------- gather: h = y + csr_sum(y) + b, accumulate BN stats ----------------
__global__ __launch_bounds__(256) void gather_kernel(
    const float* __restrict__ y, const int* __restrict__ rowptr,
    const int* __restrict__ colidx, const float* __restrict__ bias,
    float* __restrict__ h, float* __restrict__ stats, int n) {
  __shared__ float s_sum[64], s_sq[64];
  int tid = threadIdx.x;
  if (tid < 64) { s_sum[tid] = 0.f; s_sq[tid] = 0.f; }
  __syncthreads();
  int lane = tid & 63, wv = tid >> 6;
  float bv = bias[lane];
  float psum = 0.f, psq = 0.f;
  int stride = gridDim.x * 4;
  for (int node = blockIdx.x * 4 + wv; node < n; node += stride) {
    float acc = y[(size_t)node * 64 + lane] + bv;
    int beg = rowptr[node], end = rowptr[node + 1];
    int e = beg;
    for (; e + 8 <= end; e += 8) {
      int j0 = colidx[e], j1 = colidx[e + 1], j2 = colidx[e + 2], j3 = colidx[e + 3];
      int j4 = colidx[e + 4], j5 = colidx[e + 5], j6 = colidx[e + 6], j7 = colidx[e + 7];
      float v0 = y[(size_t)j0 * 64 + lane], v1 = y[(size_t)j1 * 64 + lane];
      float v2 = y[(size_t)j2 * 64 + lane], v3 = y[(size_t)j3 * 64 + lane];
      float v4 = y[(size_t)j4 * 64 + lane], v5 = y[(size_t)j5 * 64 + lane];
      float v6 = y[(size_t)j6 * 64 + lane], v7 = y[(size_t)j7 * 64 + lane];
      acc += ((v0 + v1) + (v2 + v3)) + ((v4 + v5) + (v6 + v7));
    }
    for (; e + 4 <= end; e += 4) {
      int j0 = colidx[e], j1 = colidx[e + 1], j2 = colidx[e + 2], j3 = colidx[e + 3];
      float v0 = y[(size_t)j0 * 64 + lane], v1 = y[(size_t)j1 * 64 + lane];
      float v2 = y[(size_t)j2 * 64 + lane], v3 = y[(size_t)j3 * 64 + lane];
      acc += (v0 + v1) + (v2 + v3);
    }
    for (; e < end; ++e) acc += y[(size_t)colidx[e] * 64 + lane];
    h[(size_t)node * 64 + lane] = acc;
    psum += acc;
    psq += acc * acc;
  }
  atomicAdd(&s_sum[lane], psum);
  atomicAdd(&s_sq[lane], psq);
  __syncthreads();
  if (tid < 64) {
    atomicAdd(&stats[tid], s_sum[tid]);
    atomicAdd(&stats[64 + tid], s_sq[tid]);
  }
}

// ---------------- final MLP over concat [x0|z1|z2|bnleaky(h2)] (320 -> 64) ----------------
__global__ __launch_bounds__(256) void final_mlp_kernel(
    const float* __restrict__ x0, const float* __restrict__ z1,
    const float* __restrict__ z2, const float* __restrict__ h2,
    const float* __restrict__ st2, const float* __restrict__ fw1,
    const float* __restrict__ fb1, float* __restrict__ hf,
    float* __restrict__ stats, int n) {
  __shared__ float tileT[128][NT + 4];
  __shared__ float WT[128][NT + 4];
  __shared__ float s_sum[64], s_sq[64];

  int tid = threadIdx.x;
  if (tid < 64) { s_sum[tid] = 0.f; s_sq[tid] = 0.f; }
  int nbase = blockIdx.x * NT;
  int lane = tid & 63, wave = tid >> 6;
  int o0 = (tid & 15) * 4, r0 = (tid >> 4) * 4;
  float acc[4][4] = {};
  float sc2 = st2[128 + lane], sh2 = st2[192 + lane];

  const float* srcs[4] = {x0, z1, z2, h2};
  const int dins[4] = {128, 64, 64, 64};
  int woff = 0;
  for (int seg = 0; seg < 4; ++seg) {
    const float* src = srcs[seg];
    int DIN = dins[seg];
    int sh = (DIN == 128) ? 7 : 6;
    __syncthreads();
    for (int t = tid; t < 64 * DIN; t += 256) {
      int o = t >> sh, d = t & (DIN - 1);
      WT[d][o] = fw1[o * 320 + woff + d];
    }
    for (int k = wave; k < NT; k += 4) {
      int node = nbase + k;
      float a0 = 0.f, a1 = 0.f;
      if (node < n) {
        a0 = src[(size_t)node * DIN + lane];
        if (DIN == 128) a1 = src[(size_t)node * DIN + 64 + lane];
        if (seg == 3) {  // z3 = leaky(bn(h2)) computed inline
          a0 = a0 * sc2 + sh2;
          a0 = (a0 >= 0.f) ? a0 : 0.01f * a0;
        }
      }
      tileT[lane][k] = a0;
      if (DIN == 128) tileT[64 + lane][k] = a1;
    }
    __syncthreads();
    for (int d = 0; d < DIN; ++d) {
      const float4 wv = *(const float4*)(&WT[d][o0]);
      const float4 tv = *(const float4*)(&tileT[d][r0]);
      acc[0][0] += wv.x * tv.x; acc[0][1] += wv.x * tv.y; acc[0][2] += wv.x * tv.z; acc[0][3] += wv.x * tv.w;
      acc[1][0] += wv.y * tv.x; acc[1][1] += wv.y * tv.y; acc[1][2] += wv.y * tv.z; acc[1][3] += wv.y * tv.w;
      acc[2][0] += wv.z * tv.x; acc[2][1] += wv.z * tv.y; acc[2][2] += wv.z * tv.z; acc[2][3] += wv.z * tv.w;
      acc[3][0] += wv.w * tv.x; acc[3][1] += wv.w * tv.y; acc[3][2] += wv.w * tv.z; acc[3][3] += wv.w * tv.w;
    }
    woff += DIN;
  }

#pragma unroll
  for (int i = 0; i < 4; ++i) {
    float bv = fb1[o0 + i];
    float s = 0.f, q = 0.f;
#pragma unroll
    for (int j = 0; j < 4; ++j) {
      int node = nbase + r0 + j;
      if (node < n) {
        float v = acc[i][j] + bv;
        hf[(size_t)node * 64 + o0 + i] = v;
        s += v;
        q += v * v;
      }
    }
    atomicAdd(&s_sum[o0 + i], s);
    atomicAdd(&s_sq[o0 + i], q);
  }
  __syncthreads();
  if (tid < 64) {
    atomicAdd(&stats[tid], s_sum[tid]);
    atomicAdd(&stats[64 + tid], s_sq[tid]);
  }
}

// ---------------- BN finalize: scale/shift ----------------
__global__ void bn_finalize_kernel(float* __restrict__ st, const float* __restrict__ g,
                                   const float* __restrict__ be, float inv_n) {
  int o = threadIdx.x;
  if (o < 64) {
    float mean = st[o] * inv_n;
    float var = st[64 + o] * inv_n - mean * mean;
    float sc = g[o] * rsqrtf(var + 1e-5f);
    st[128 + o] = sc;
    st[192 + o] = be[o] - mean * sc;
  }
}

// ---------------- head: sigmoid(leaky(bn(hf)) @ fw2^T + fb2) ----------------
__global__ __launch_bounds__(256) void final_out_kernel(const float* __restrict__ hf,
                                                        const float* __restrict__ st,
                                                        const float* __restrict__ fw2,
                                                        const float* __restrict__ fb2,
                                                        float* __restrict__ out, int n) {
  int lane = threadIdx.x & 63;
  int node = blockIdx.x * 4 + (threadIdx.x >> 6);
  if (node >= n) return;
  float v = hf[(size_t)node * 64 + lane] * st[128 + lane] + st[192 + lane];
  v = (v >= 0.f) ? v : 0.01f * v;
  v *= fw2[lane];
#pragma unroll
  for (int off = 32; off > 0; off >>= 1) v += __shfl_xor(v, off);
  if (lane == 0) out[node] = 1.f / (1.f + expf(-(v + fb2[0])));
}

extern "C" void kernel_launch(void* const* d_in, const int* in_sizes, int n_in,
                              void* d_out, int out_size, void* d_ws, size_t ws_size,
                              hipStream_t stream) {
  const int* node_deg = (const int*)d_in[0];
  const int* node_lab = (const int*)d_in[1];
  const int* ei = (const int*)d_in[2];
  const float* emb_deg = (const float*)d_in[3];
  const float* emb_lab = (const float*)d_in[4];
  const float* w0 = (const float*)d_in[5];
  const float* b0 = (const float*)d_in[6];
  const float* g0 = (const float*)d_in[7];
  const float* be0 = (const float*)d_in[8];
  const float* w1 = (const float*)d_in[9];
  const float* b1 = (const float*)d_in[10];
  const float* g1 = (const float*)d_in[11];
  const float* be1 = (const float*)d_in[12];
  const float* w2 = (const float*)d_in[13];
  const float* b2 = (const float*)d_in[14];
  const float* g2 = (const float*)d_in[15];
  const float* be2 = (const float*)d_in[16];
  const float* fw1 = (const float*)d_in[17];
  const float* fb1 = (const float*)d_in[18];
  const float* fg = (const float*)d_in[19];
  const float* fbe = (const float*)d_in[20];
  const float* fw2 = (const float*)d_in[21];
  const float* fb2 = (const float*)d_in[22];

  const int N = in_sizes[0];
  const int E = in_sizes[2] / 2;
  const int* src = ei;
  const int* dst = ei + E;

  char* ws = (char*)d_ws;
  size_t off = 0;
  auto alloc = [&](size_t bytes) {
    void* p = ws + off;
    off += (bytes + 255) & ~(size_t)255;
    return p;
  };
  float* x0 = (float*)alloc((size_t)N * 128 * 4);
  float* z1 = (float*)alloc((size_t)N * 64 * 4);
  float* z2 = (float*)alloc((size_t)N * 64 * 4);
  float* h = (float*)alloc((size_t)N * 64 * 4);
  float* y = (float*)alloc((size_t)N * 64 * 4);
  int* rowptr = (int*)alloc((size_t)(N + 1) * 4);
  int* cursor = (int*)alloc((size_t)N * 4);
  int* counts = (int*)alloc((size_t)N * 4);
  int* colidx = (int*)alloc((size_t)E * 4);
  int* bsums = (int*)alloc(64 * 4);
  int* boffs = (int*)alloc(64 * 4);
  float* stats = (float*)alloc(4 * 256 * 4);

  hipMemsetAsync(counts, 0, (size_t)N * 4, stream);
  hipMemsetAsync(stats, 0, 4 * 256 * 4, stream);

  embed_kernel<<<(N * 32 + 255) / 256, 256, 0, stream>>>(node_deg, node_lab, emb_deg,
                                                         emb_lab, (float4*)x0, N);
  hist_kernel<<<(E + 255) / 256, 256, 0, stream>>>(dst, counts, E);
  int nb = (N + 2047) / 2048;
  scan1_kernel<<<nb, 256, 0, stream>>>(counts, rowptr, bsums, N);
  scan2_kernel<<<1, 64, 0, stream>>>(bsums, boffs, nb);
  scan3_kernel<<<(N + 255) / 256, 256, 0, stream>>>(rowptr, boffs, N);
  cursor_kernel<<<(N + 255) / 256, 256, 0, stream>>>(cursor, rowptr, N);
  scatter_kernel<<<(E + 255) / 256, 256, 0, stream>>>(src, dst, cursor, colidx, E);

  int ngrid = (N + NT - 1) / NT;
  int ggrid = 2048;  // gather grid: ~8 blocks/CU, grid-stride over nodes

  // layer 0: y0 = x0 @ W0^T ; h0 = y0 + agg(y0) + b0 ; stats0
  gemm0_kernel<<<ngrid, 256, 0, stream>>>(x0, w0, y, N);
  gather_kernel<<<ggrid, 256, 0, stream>>>(y, rowptr, colidx, b0, h, stats, N);
  bn_finalize_kernel<<<1, 64, 0, stream>>>(stats, g0, be0, 1.0f / N);
  // layer 1
  gemm_bn_kernel<<<ngrid, 256, 0, stream>>>(h, stats, w1, z1, y, N);
  gather_kernel<<<ggrid, 256, 0, stream>>>(y, rowptr, colidx, b1, h, stats + 256, N);
  bn_finalize_kernel<<<1, 64, 0, stream>>>(stats + 256, g1, be1, 1.0f / N);
  // layer 2
  gemm_bn_kernel<<<ngrid, 256, 0, stream>>>(h, stats + 256, w2, z2, y, N);
  gather_kernel<<<ggrid, 256, 0, stream>>>(y, rowptr, colidx, b2, h, stats + 512, N);
  bn_finalize_kernel<<<1, 64, 0, stream>>>(stats + 512, g2, be2, 1.0f / N);
  // final MLP 320 -> 64 (z3 inline from h2)
  final_mlp_kernel<<<ngrid, 256, 0, stream>>>(x0, z1, z2, h, stats + 512, fw1, fb1, y,
                                              stats + 768, N);
  bn_finalize_kernel<<<1, 64, 0, stream>>>(stats + 768, fg, fbe, 1.0f / N);
  final_out_kernel<<<(N + 3) / 4, 256, 0, stream>>>(y, stats + 768, fw2, fb2,
                                                    (float*)d_out, N);
}

// Round 3
// 779.690 us; speedup vs baseline: 9.2483x; 1.2093x over previous
//
#include <hip/hip_runtime.h>
#include <math.h>

typedef __bf16 bf16;
typedef __attribute__((ext_vector_type(8))) __bf16 bf16x8;
typedef __attribute__((ext_vector_type(4))) float f32x4;

// ---------------- embedding: x0 = concat(emb_deg[deg], emb_lab[lab]) as bf16 ----------------
__global__ __launch_bounds__(256) void embed_kernel(
    const int* __restrict__ deg, const int* __restrict__ lab,
    const float* __restrict__ ed, const float* __restrict__ el,
    bf16* __restrict__ x0, int n) {
  int idx = blockIdx.x * 256 + threadIdx.x;  // one 8-elem chunk per thread
  if (idx >= n * 16) return;                 // 128 elems = 16 chunks per node
  int node = idx >> 4, q = idx & 15;
  const float* srcp = (q < 8) ? (ed + (size_t)deg[node] * 64 + q * 8)
                              : (el + (size_t)lab[node] * 64 + (q - 8) * 8);
  float4 a = ((const float4*)srcp)[0];
  float4 b = ((const float4*)srcp)[1];
  union { bf16 h[8]; uint4 u; } out;
  out.h[0] = (bf16)a.x; out.h[1] = (bf16)a.y; out.h[2] = (bf16)a.z; out.h[3] = (bf16)a.w;
  out.h[4] = (bf16)b.x; out.h[5] = (bf16)b.y; out.h[6] = (bf16)b.z; out.h[7] = (bf16)b.w;
  *(uint4*)(x0 + (size_t)idx * 8) = out.u;
}

// ---------------- CSR build ----------------
__global__ __launch_bounds__(256) void hist_kernel(const int* __restrict__ dst,
                                                   int* __restrict__ counts, int E) {
  int e = blockIdx.x * 256 + threadIdx.x;
  if (e < E) atomicAdd(&counts[dst[e]], 1);
}

__global__ __launch_bounds__(256) void scan1_kernel(const int* __restrict__ counts,
                                                    int* __restrict__ rowptr,
                                                    int* __restrict__ bsums, int n) {
  __shared__ int lds[256];
  int tid = threadIdx.x;
  int base = blockIdx.x * 2048;
  int vals[8];
  int s = 0;
#pragma unroll
  for (int k = 0; k < 8; ++k) {
    int idx = base + tid * 8 + k;
    vals[k] = (idx < n) ? counts[idx] : 0;
    s += vals[k];
  }
  lds[tid] = s;
  __syncthreads();
  for (int off = 1; off < 256; off <<= 1) {
    int v = (tid >= off) ? lds[tid - off] : 0;
    __syncthreads();
    lds[tid] += v;
    __syncthreads();
  }
  int run = lds[tid] - s;
#pragma unroll
  for (int k = 0; k < 8; ++k) {
    int idx = base + tid * 8 + k;
    run += vals[k];
    if (idx < n) rowptr[idx + 1] = run;
  }
  if (tid == 255) bsums[blockIdx.x] = lds[255];
}

__global__ void scan2_kernel(const int* __restrict__ bsums, int* __restrict__ boffs, int nb) {
  if (threadIdx.x == 0) {
    int run = 0;
    for (int i = 0; i < nb; ++i) { boffs[i] = run; run += bsums[i]; }
  }
}

__global__ __launch_bounds__(256) void scan3_kernel(int* __restrict__ rowptr,
                                                    const int* __restrict__ boffs, int n) {
  int idx = blockIdx.x * 256 + threadIdx.x;
  if (idx == 0) rowptr[0] = 0;
  if (idx < n) rowptr[idx + 1] += boffs[idx >> 11];
}

__global__ __launch_bounds__(256) void cursor_kernel(int* __restrict__ cursor,
                                                     const int* __restrict__ rowptr, int n) {
  int idx = blockIdx.x * 256 + threadIdx.x;
  if (idx < n) cursor[idx] = rowptr[idx];
}

__global__ __launch_bounds__(256) void scatter_kernel(const int* __restrict__ src,
                                                      const int* __restrict__ dst,
                                                      int* __restrict__ cursor,
                                                      int* __restrict__ colidx, int E) {
  int e = blockIdx.x * 256 + threadIdx.x;
  if (e < E) {
    int d = dst[e];
    int pos = atomicAdd(&cursor[d], 1);
    colidx[pos] = src[e];
  }
}

// ---------------- MFMA GEMM 0: y = x0(bf16) @ W0^T, fp32 out ----------------
__global__ __launch_bounds__(256) void mfma_gemm0(
    const bf16* __restrict__ x, const float* __restrict__ W,
    float* __restrict__ y, int n) {
  __shared__ bf16 As[64][136];  // [node][d], pad 8 -> 2-way-only bank aliasing
  __shared__ bf16 Bs[64][136];  // [o][d]
  int tid = threadIdx.x;
  int nbase = blockIdx.x * 64;
  {
    int r = tid >> 2, c = tid & 3;  // r: row, c: 32-elem chunk
    int node = nbase + r;
    uint4 v[4] = {};
    if (node < n) {
      const uint4* p = (const uint4*)(x + (size_t)node * 128 + c * 32);
#pragma unroll
      for (int j = 0; j < 4; ++j) v[j] = p[j];
    }
#pragma unroll
    for (int j = 0; j < 4; ++j) *(uint4*)&As[r][c * 32 + j * 8] = v[j];
    const float4* wp = (const float4*)(W + r * 128 + c * 32);
#pragma unroll
    for (int j = 0; j < 4; ++j) {
      float4 f0 = wp[j * 2], f1 = wp[j * 2 + 1];
      union { bf16 h[8]; uint4 u; } t;
      t.h[0] = (bf16)f0.x; t.h[1] = (bf16)f0.y; t.h[2] = (bf16)f0.z; t.h[3] = (bf16)f0.w;
      t.h[4] = (bf16)f1.x; t.h[5] = (bf16)f1.y; t.h[6] = (bf16)f1.z; t.h[7] = (bf16)f1.w;
      *(uint4*)&Bs[r][c * 32 + j * 8] = t.u;
    }
  }
  __syncthreads();
  int l = tid & 63, w = tid >> 6, m = l & 15, quad = l >> 4;
  f32x4 acc[4] = {{0.f, 0.f, 0.f, 0.f}, {0.f, 0.f, 0.f, 0.f},
                  {0.f, 0.f, 0.f, 0.f}, {0.f, 0.f, 0.f, 0.f}};
#pragma unroll
  for (int k0 = 0; k0 < 128; k0 += 32) {
    bf16x8 a = *(const bf16x8*)&As[w * 16 + m][k0 + quad * 8];
#pragma unroll
    for (int t = 0; t < 4; ++t) {
      bf16x8 b = *(const bf16x8*)&Bs[t * 16 + m][k0 + quad * 8];
      acc[t] = __builtin_amdgcn_mfma_f32_16x16x32_bf16(a, b, acc[t], 0, 0, 0);
    }
  }
#pragma unroll
  for (int t = 0; t < 4; ++t)
#pragma unroll
    for (int r4 = 0; r4 < 4; ++r4) {
      int node = nbase + w * 16 + quad * 4 + r4;
      if (node < n) y[(size_t)node * 64 + t * 16 + m] = acc[t][r4];
    }
}

// ------- MFMA GEMM (layers 1,2): z = leaky(bn(hin)) [bf16 out]; y = z @ W^T -------
__global__ __launch_bounds__(256) void mfma_gemm_bn(
    const float* __restrict__ hin, const float* __restrict__ st,
    const float* __restrict__ W, bf16* __restrict__ z,
    float* __restrict__ y, int n) {
  __shared__ bf16 As[64][72];
  __shared__ bf16 Bs[64][72];
  int tid = threadIdx.x;
  int nbase = blockIdx.x * 64;
  {
    int r = tid >> 2, c = tid & 3;  // 16-elem chunk
    int node = nbase + r;
    union { bf16 h[16]; uint4 u[2]; } t;
    if (node < n) {
      const float4* p = (const float4*)(hin + (size_t)node * 64 + c * 16);
#pragma unroll
      for (int j = 0; j < 4; ++j) {
        float4 f = p[j];
        int d = c * 16 + j * 4;
        float v0 = f.x * st[128 + d] + st[192 + d];
        float v1 = f.y * st[129 + d] + st[193 + d];
        float v2 = f.z * st[130 + d] + st[194 + d];
        float v3 = f.w * st[131 + d] + st[195 + d];
        v0 = (v0 >= 0.f) ? v0 : 0.01f * v0;
        v1 = (v1 >= 0.f) ? v1 : 0.01f * v1;
        v2 = (v2 >= 0.f) ? v2 : 0.01f * v2;
        v3 = (v3 >= 0.f) ? v3 : 0.01f * v3;
        t.h[j * 4 + 0] = (bf16)v0; t.h[j * 4 + 1] = (bf16)v1;
        t.h[j * 4 + 2] = (bf16)v2; t.h[j * 4 + 3] = (bf16)v3;
      }
      *(uint4*)(z + (size_t)node * 64 + c * 16) = t.u[0];
      *(uint4*)(z + (size_t)node * 64 + c * 16 + 8) = t.u[1];
    } else {
      t.u[0] = uint4{0, 0, 0, 0}; t.u[1] = uint4{0, 0, 0, 0};
    }
    *(uint4*)&As[r][c * 16] = t.u[0];
    *(uint4*)&As[r][c * 16 + 8] = t.u[1];
    const float4* wp = (const float4*)(W + r * 64 + c * 16);
#pragma unroll
    for (int j = 0; j < 2; ++j) {
      float4 f0 = wp[j * 2], f1 = wp[j * 2 + 1];
      union { bf16 h[8]; uint4 u; } tw;
      tw.h[0] = (bf16)f0.x; tw.h[1] = (bf16)f0.y; tw.h[2] = (bf16)f0.z; tw.h[3] = (bf16)f0.w;
      tw.h[4] = (bf16)f1.x; tw.h[5] = (bf16)f1.y; tw.h[6] = (bf16)f1.z; tw.h[7] = (bf16)f1.w;
      *(uint4*)&Bs[r][c * 16 + j * 8] = tw.u;
    }
  }
  __syncthreads();
  int l = tid & 63, w = tid >> 6, m = l & 15, quad = l >> 4;
  f32x4 acc[4] = {{0.f, 0.f, 0.f, 0.f}, {0.f, 0.f, 0.f, 0.f},
                  {0.f, 0.f, 0.f, 0.f}, {0.f, 0.f, 0.f, 0.f}};
#pragma unroll
  for (int k0 = 0; k0 < 64; k0 += 32) {
    bf16x8 a = *(const bf16x8*)&As[w * 16 + m][k0 + quad * 8];
#pragma unroll
    for (int t = 0; t < 4; ++t) {
      bf16x8 b = *(const bf16x8*)&Bs[t * 16 + m][k0 + quad * 8];
      acc[t] = __builtin_amdgcn_mfma_f32_16x16x32_bf16(a, b, acc[t], 0, 0, 0);
    }
  }
#pragma unroll
  for (int t = 0; t < 4; ++t)
#pragma unroll
    for (int r4 = 0; r4 < 4; ++r4) {
      int node = nbase + w * 16 + quad * 4 + r4;
      if (node < n) y[(size_t)node * 64 + t * 16 + m] = acc[t][r4];
    }
}

// ---------------- gather: h = y + csr_sum(y) + b, accumulate BN stats (all fp32) ----------------
__global__ __launch_bounds__(256) void gather_kernel(
    const float* __restrict__ y, const int* __restrict__ rowptr,
    const int* __restrict__ colidx, const float* __restrict__ bias,
    float* __restrict__ h, float* __restrict__ stats, int n) {
  __shared__ float s_sum[64], s_sq[64];
  int tid = threadIdx.x;
  if (tid < 64) { s_sum[tid] = 0.f; s_sq[tid] = 0.f; }
  __syncthreads();
  int lane = tid & 63, wv = tid >> 6;
  float bv = bias[lane];
  float psum = 0.f, psq = 0.f;
  int stride = gridDim.x * 4;
  for (int node = blockIdx.x * 4 + wv; node < n; node += stride) {
    float acc = y[(size_t)node * 64 + lane] + bv;
    int beg = rowptr[node], end = rowptr[node + 1];
    int e = beg;
    for (; e + 8 <= end; e += 8) {
      int j0 = colidx[e], j1 = colidx[e + 1], j2 = colidx[e + 2], j3 = colidx[e + 3];
      int j4 = colidx[e + 4], j5 = colidx[e + 5], j6 = colidx[e + 6], j7 = colidx[e + 7];
      float v0 = y[(size_t)j0 * 64 + lane], v1 = y[(size_t)j1 * 64 + lane];
      float v2 = y[(size_t)j2 * 64 + lane], v3 = y[(size_t)j3 * 64 + lane];
      float v4 = y[(size_t)j4 * 64 + lane], v5 = y[(size_t)j5 * 64 + lane];
      float v6 = y[(size_t)j6 * 64 + lane], v7 = y[(size_t)j7 * 64 + lane];
      acc += ((v0 + v1) + (v2 + v3)) + ((v4 + v5) + (v6 + v7));
    }
    for (; e + 4 <= end; e += 4) {
      int j0 = colidx[e], j1 = colidx[e + 1], j2 = colidx[e + 2], j3 = colidx[e + 3];
      float v0 = y[(size_t)j0 * 64 + lane], v1 = y[(size_t)j1 * 64 + lane];
      float v2 = y[(size_t)j2 * 64 + lane], v3 = y[(size_t)j3 * 64 + lane];
      acc += (v0 + v1) + (v2 + v3);
    }
    for (; e < end; ++e) acc += y[(size_t)colidx[e] * 64 + lane];
    h[(size_t)node * 64 + lane] = acc;
    psum += acc;
    psq += acc * acc;
  }
  atomicAdd(&s_sum[lane], psum);
  atomicAdd(&s_sq[lane], psq);
  __syncthreads();
  if (tid < 64) {
    atomicAdd(&stats[tid], s_sum[tid]);
    atomicAdd(&stats[64 + tid], s_sq[tid]);
  }
}

// ---------------- final MLP over concat [x0|z1|z2|bnleaky(h2)] (320 -> 64), MFMA ----------------
__global__ __launch_bounds__(256) void mfma_final(
    const bf16* __restrict__ x0, const bf16* __restrict__ z1,
    const bf16* __restrict__ z2, const float* __restrict__ h2,
    const float* __restrict__ st2, const float* __restrict__ fw1,
    const float* __restrict__ fb1, float* __restrict__ hf,
    float* __restrict__ stats, int n) {
  __shared__ bf16 As[64][136];
  __shared__ bf16 Bs[64][136];
  __shared__ float s_sum[64], s_sq[64];
  int tid = threadIdx.x;
  if (tid < 64) { s_sum[tid] = 0.f; s_sq[tid] = 0.f; }
  int nbase = blockIdx.x * 64;
  int l = tid & 63, w = tid >> 6, m = l & 15, quad = l >> 4;
  int r = tid >> 2, c = tid & 3;
  int node_r = nbase + r;
  f32x4 acc[4] = {{0.f, 0.f, 0.f, 0.f}, {0.f, 0.f, 0.f, 0.f},
                  {0.f, 0.f, 0.f, 0.f}, {0.f, 0.f, 0.f, 0.f}};

#pragma unroll
  for (int seg = 0; seg < 4; ++seg) {
    __syncthreads();  // LDS reuse guard
    if (seg == 0) {
      // A: x0 bf16, DIN=128
      uint4 v[4] = {};
      if (node_r < n) {
        const uint4* p = (const uint4*)(x0 + (size_t)node_r * 128 + c * 32);
#pragma unroll
        for (int j = 0; j < 4; ++j) v[j] = p[j];
      }
#pragma unroll
      for (int j = 0; j < 4; ++j) *(uint4*)&As[r][c * 32 + j * 8] = v[j];
      // B: fw1[o][0..127]
      const float4* wp = (const float4*)(fw1 + r * 320 + c * 32);
#pragma unroll
      for (int j = 0; j < 4; ++j) {
        float4 f0 = wp[j * 2], f1 = wp[j * 2 + 1];
        union { bf16 h[8]; uint4 u; } t;
        t.h[0] = (bf16)f0.x; t.h[1] = (bf16)f0.y; t.h[2] = (bf16)f0.z; t.h[3] = (bf16)f0.w;
        t.h[4] = (bf16)f1.x; t.h[5] = (bf16)f1.y; t.h[6] = (bf16)f1.z; t.h[7] = (bf16)f1.w;
        *(uint4*)&Bs[r][c * 32 + j * 8] = t.u;
      }
    } else if (seg < 3) {
      const bf16* zz = (seg == 1) ? z1 : z2;
      uint4 v[2] = {};
      if (node_r < n) {
        const uint4* p = (const uint4*)(zz + (size_t)node_r * 64 + c * 16);
        v[0] = p[0]; v[1] = p[1];
      }
      *(uint4*)&As[r][c * 16] = v[0];
      *(uint4*)&As[r][c * 16 + 8] = v[1];
      const float4* wp = (const float4*)(fw1 + r * 320 + (seg == 1 ? 128 : 192) + c * 16);
#pragma unroll
      for (int j = 0; j < 2; ++j) {
        float4 f0 = wp[j * 2], f1 = wp[j * 2 + 1];
        union { bf16 h[8]; uint4 u; } t;
        t.h[0] = (bf16)f0.x; t.h[1] = (bf16)f0.y; t.h[2] = (bf16)f0.z; t.h[3] = (bf16)f0.w;
        t.h[4] = (bf16)f1.x; t.h[5] = (bf16)f1.y; t.h[6] = (bf16)f1.z; t.h[7] = (bf16)f1.w;
        *(uint4*)&Bs[r][c * 16 + j * 8] = t.u;
      }
    } else {
      // A: z3 = leaky(bn(h2)) inline, fp32 -> bf16
      union { bf16 h[16]; uint4 u[2]; } t;
      if (node_r < n) {
        const float4* p = (const float4*)(h2 + (size_t)node_r * 64 + c * 16);
#pragma unroll
        for (int j = 0; j < 4; ++j) {
          float4 f = p[j];
          int d = c * 16 + j * 4;
          float v0 = f.x * st2[128 + d] + st2[192 + d];
          float v1 = f.y * st2[129 + d] + st2[193 + d];
          float v2 = f.z * st2[130 + d] + st2[194 + d];
          float v3 = f.w * st2[131 + d] + st2[195 + d];
          v0 = (v0 >= 0.f) ? v0 : 0.01f * v0;
          v1 = (v1 >= 0.f) ? v1 : 0.01f * v1;
          v2 = (v2 >= 0.f) ? v2 : 0.01f * v2;
          v3 = (v3 >= 0.f) ? v3 : 0.01f * v3;
          t.h[j * 4 + 0] = (bf16)v0; t.h[j * 4 + 1] = (bf16)v1;
          t.h[j * 4 + 2] = (bf16)v2; t.h[j * 4 + 3] = (bf16)v3;
        }
      } else {
        t.u[0] = uint4{0, 0, 0, 0}; t.u[1] = uint4{0, 0, 0, 0};
      }
      *(uint4*)&As[r][c * 16] = t.u[0];
      *(uint4*)&As[r][c * 16 + 8] = t.u[1];
      const float4* wp = (const float4*)(fw1 + r * 320 + 256 + c * 16);
#pragma unroll
      for (int j = 0; j < 2; ++j) {
        float4 f0 = wp[j * 2], f1 = wp[j * 2 + 1];
        union { bf16 h[8]; uint4 u; } tw;
        tw.h[0] = (bf16)f0.x; tw.h[1] = (bf16)f0.y; tw.h[2] = (bf16)f0.z; tw.h[3] = (bf16)f0.w;
        tw.h[4] = (bf16)f1.x; tw.h[5] = (bf16)f1.y; tw.h[6] = (bf16)f1.z; tw.h[7] = (bf16)f1.w;
        *(uint4*)&Bs[r][c * 16 + j * 8] = tw.u;
      }
    }
    __syncthreads();
    int kmax = (seg == 0) ? 128 : 64;
    for (int k0 = 0; k0 < kmax; k0 += 32) {
      bf16x8 a = *(const bf16x8*)&As[w * 16 + m][k0 + quad * 8];
#pragma unroll
      for (int t = 0; t < 4; ++t) {
        bf16x8 b = *(const bf16x8*)&Bs[t * 16 + m][k0 + quad * 8];
        acc[t] = __builtin_amdgcn_mfma_f32_16x16x32_bf16(a, b, acc[t], 0, 0, 0);
      }
    }
  }

#pragma unroll
  for (int t = 0; t < 4; ++t) {
    int o = t * 16 + m;
    float bv = fb1[o];
    float s = 0.f, q = 0.f;
#pragma unroll
    for (int r4 = 0; r4 < 4; ++r4) {
      int node = nbase + w * 16 + quad * 4 + r4;
      if (node < n) {
        float v = acc[t][r4] + bv;
        hf[(size_t)node * 64 + o] = v;
        s += v;
        q += v * v;
      }
    }
    atomicAdd(&s_sum[o], s);
    atomicAdd(&s_sq[o], q);
  }
  __syncthreads();
  if (tid < 64) {
    atomicAdd(&stats[tid], s_sum[tid]);
    atomicAdd(&stats[64 + tid], s_sq[tid]);
  }
}

// ---------------- BN finalize: scale/shift ----------------
__global__ void bn_finalize_kernel(float* __restrict__ st, const float* __restrict__ g,
                                   const float* __restrict__ be, float inv_n) {
  int o = threadIdx.x;
  if (o < 64) {
    float mean = st[o] * inv_n;
    float var = st[64 + o] * inv_n - mean * mean;
    float sc = g[o] * rsqrtf(var + 1e-5f);
    st[128 + o] = sc;
    st[192 + o] = be[o] - mean * sc;
  }
}

// ---------------- head: sigmoid(leaky(bn(hf)) @ fw2^T + fb2) ----------------
__global__ __launch_bounds__(256) void final_out_kernel(const float* __restrict__ hf,
                                                        const float* __restrict__ st,
                                                        const float* __restrict__ fw2,
                                                        const float* __restrict__ fb2,
                                                        float* __restrict__ out, int n) {
  int lane = threadIdx.x & 63;
  int node = blockIdx.x * 4 + (threadIdx.x >> 6);
  if (node >= n) return;
  float v = hf[(size_t)node * 64 + lane] * st[128 + lane] + st[192 + lane];
  v = (v >= 0.f) ? v : 0.01f * v;
  v *= fw2[lane];
#pragma unroll
  for (int off = 32; off > 0; off >>= 1) v += __shfl_xor(v, off);
  if (lane == 0) out[node] = 1.f / (1.f + expf(-(v + fb2[0])));
}

extern "C" void kernel_launch(void* const* d_in, const int* in_sizes, int n_in,
                              void* d_out, int out_size, void* d_ws, size_t ws_size,
                              hipStream_t stream) {
  const int* node_deg = (const int*)d_in[0];
  const int* node_lab = (const int*)d_in[1];
  const int* ei = (const int*)d_in[2];
  const float* emb_deg = (const float*)d_in[3];
  const float* emb_lab = (const float*)d_in[4];
  const float* w0 = (const float*)d_in[5];
  const float* b0 = (const float*)d_in[6];
  const float* g0 = (const float*)d_in[7];
  const float* be0 = (const float*)d_in[8];
  const float* w1 = (const float*)d_in[9];
  const float* b1 = (const float*)d_in[10];
  const float* g1 = (const float*)d_in[11];
  const float* be1 = (const float*)d_in[12];
  const float* w2 = (const float*)d_in[13];
  const float* b2 = (const float*)d_in[14];
  const float* g2 = (const float*)d_in[15];
  const float* be2 = (const float*)d_in[16];
  const float* fw1 = (const float*)d_in[17];
  const float* fb1 = (const float*)d_in[18];
  const float* fg = (const float*)d_in[19];
  const float* fbe = (const float*)d_in[20];
  const float* fw2 = (const float*)d_in[21];
  const float* fb2 = (const float*)d_in[22];

  const int N = in_sizes[0];
  const int E = in_sizes[2] / 2;
  const int* src = ei;
  const int* dst = ei + E;

  char* ws = (char*)d_ws;
  size_t off = 0;
  auto alloc = [&](size_t bytes) {
    void* p = ws + off;
    off += (bytes + 255) & ~(size_t)255;
    return p;
  };
  bf16* x0 = (bf16*)alloc((size_t)N * 128 * 2);
  bf16* z1 = (bf16*)alloc((size_t)N * 64 * 2);
  bf16* z2 = (bf16*)alloc((size_t)N * 64 * 2);
  float* h = (float*)alloc((size_t)N * 64 * 4);
  float* y = (float*)alloc((size_t)N * 64 * 4);
  int* rowptr = (int*)alloc((size_t)(N + 1) * 4);
  int* cursor = (int*)alloc((size_t)N * 4);
  int* counts = (int*)alloc((size_t)N * 4);
  int* colidx = (int*)alloc((size_t)E * 4);
  int* bsums = (int*)alloc(64 * 4);
  int* boffs = (int*)alloc(64 * 4);
  float* stats = (float*)alloc(4 * 256 * 4);

  hipMemsetAsync(counts, 0, (size_t)N * 4, stream);
  hipMemsetAsync(stats, 0, 4 * 256 * 4, stream);

  embed_kernel<<<(N * 16 + 255) / 256, 256, 0, stream>>>(node_deg, node_lab, emb_deg,
                                                         emb_lab, x0, N);
  hist_kernel<<<(E + 255) / 256, 256, 0, stream>>>(dst, counts, E);
  int nb = (N + 2047) / 2048;
  scan1_kernel<<<nb, 256, 0, stream>>>(counts, rowptr, bsums, N);
  scan2_kernel<<<1, 64, 0, stream>>>(bsums, boffs, nb);
  scan3_kernel<<<(N + 255) / 256, 256, 0, stream>>>(rowptr, boffs, N);
  cursor_kernel<<<(N + 255) / 256, 256, 0, stream>>>(cursor, rowptr, N);
  scatter_kernel<<<(E + 255) / 256, 256, 0, stream>>>(src, dst, cursor, colidx, E);

  int ngrid = (N + 63) / 64;
  int ggrid = 2048;

  // layer 0
  mfma_gemm0<<<ngrid, 256, 0, stream>>>(x0, w0, y, N);
  gather_kernel<<<ggrid, 256, 0, stream>>>(y, rowptr, colidx, b0, h, stats, N);
  bn_finalize_kernel<<<1, 64, 0, stream>>>(stats, g0, be0, 1.0f / N);
  // layer 1
  mfma_gemm_bn<<<ngrid, 256, 0, stream>>>(h, stats, w1, z1, y, N);
  gather_kernel<<<ggrid, 256, 0, stream>>>(y, rowptr, colidx, b1, h, stats + 256, N);
  bn_finalize_kernel<<<1, 64, 0, stream>>>(stats + 256, g1, be1, 1.0f / N);
  // layer 2
  mfma_gemm_bn<<<ngrid, 256, 0, stream>>>(h, stats + 256, w2, z2, y, N);
  gather_kernel<<<ggrid, 256, 0, stream>>>(y, rowptr, colidx, b2, h, stats + 512, N);
  bn_finalize_kernel<<<1, 64, 0, stream>>>(stats + 512, g2, be2, 1.0f / N);
  // final MLP 320 -> 64 (z3 inline from h2)
  mfma_final<<<ngrid, 256, 0, stream>>>(x0, z1, z2, h, stats + 512, fw1, fb1, y,
                                        stats + 768, N);
  bn_finalize_kernel<<<1, 64, 0, stream>>>(stats + 768, fg, fbe, 1.0f / N);
  final_out_kernel<<<(N + 3) / 4, 256, 0, stream>>>(y, stats + 768, fw2, fb2,
                                                    (float*)d_out, N);
}